// Round 4
// baseline (269.611 us; speedup 1.0000x reference)
//
#include <hip/hip_runtime.h>

typedef __bf16 bf16;
typedef short s16x8 __attribute__((ext_vector_type(8)));   // 8 bf16 bit-patterns for MFMA frags
typedef __bf16 b16x8 __attribute__((ext_vector_type(8)));  // 8 bf16 for scalar convert paths
typedef float f32x4 __attribute__((ext_vector_type(4)));

#define B_   4096
#define L_   50
#define SX   136   // Xs row stride (bf16): 128 + 8 pad (272 B rows, 16B aligned)

// ws layout (bf16 elems unless noted)
#define OFF_W1T  0        // [64][128]  gv_w1^T
#define OFF_W2T  8192     // [64][64]   gv_w2^T
#define OFF_W3T  12288    // [64][64]   gv_w3^T
#define OFF_WCAT 16384    // [64][128]  [W3@A1_top ; A1_bot]^T
#define OFF_A2T  24576    // [64][64]   att_w2^T
#define OFF_R1T  28672    // [64][128]  wr1^T
#define OFF_R2T  36864    // [64][64]   wr2^T
#define WT_TOTAL 40960
#define BIAS1P_BYTE 81920 // float[64]  gv_b3@A1_top + att_b1

__device__ __forceinline__ unsigned short f2b(float f) {
    __bf16 h = (__bf16)f;
    return __builtin_bit_cast(unsigned short, h);
}
__device__ __forceinline__ unsigned pack2(float a, float b) {
    return (unsigned)f2b(a) | ((unsigned)f2b(b) << 16);
}

// O = act(A @ W + bias): 16 rows x 64 cols per wave. A in LDS (stride sA), Wt[n][k] global bf16.
// HW-verified layouts: A[m=lane&15][k=quad*8+j]; B[k=quad*8+j][n=lane&15]; D col=lane&15, row=quad*4+reg.
// Same-wave LDS WAR/RAW (O0 overlapping A0) is safe: per-wave DS pipe is in-order.
template<int KT, bool RELU>
__device__ __forceinline__ void layer(const bf16* A0, int sA,
                                      const bf16* __restrict__ Wt, const float* __restrict__ bias,
                                      bf16* O0, int sO, int lane)
{
    const int m = lane & 15, quad = lane >> 4;
    f32x4 acc[4] = {};
#pragma unroll
    for (int kt = 0; kt < KT; ++kt) {
        s16x8 a = *(const s16x8*)(A0 + m * sA + kt * 32 + quad * 8);
#pragma unroll
        for (int nt = 0; nt < 4; ++nt) {
            s16x8 b = *(const s16x8*)(Wt + (nt * 16 + m) * (KT * 32) + kt * 32 + quad * 8);
            acc[nt] = __builtin_amdgcn_mfma_f32_16x16x32_bf16(a, b, acc[nt], 0, 0, 0);
        }
    }
#pragma unroll
    for (int nt = 0; nt < 4; ++nt) {
        int c = nt * 16 + m;
        float bv = bias[c];
#pragma unroll
        for (int r4 = 0; r4 < 4; ++r4) {
            float v = acc[nt][r4] + bv;
            if (RELU) v = fmaxf(v, 0.f);
            O0[(quad * 4 + r4) * sO + c] = (bf16)v;
        }
    }
}

// ---------------- prep: bf16 transposed weights, WCAT fold, bias1' ----------------
extern "C" __global__ void prep_weights(const float* __restrict__ w1, const float* __restrict__ w2,
                                        const float* __restrict__ w3, const float* __restrict__ a1,
                                        const float* __restrict__ a2, const float* __restrict__ r1,
                                        const float* __restrict__ r2, const float* __restrict__ gb3,
                                        const float* __restrict__ ab1,
                                        bf16* __restrict__ wt, float* __restrict__ bias1p)
{
    int i = blockIdx.x * blockDim.x + threadIdx.x;
    if (i >= WT_TOTAL + 64) return;
    if (i >= WT_TOTAL) {                       // bias1'[n] = ab1[n] + sum_t gb3[t]*a1[t][n]
        int n = i - WT_TOTAL;
        float s0 = ab1[n], s1 = 0.f, s2 = 0.f, s3 = 0.f;
#pragma unroll
        for (int t = 0; t < 64; t += 4) {
            s0 = fmaf(gb3[t],     a1[t * 64 + n],       s0);
            s1 = fmaf(gb3[t + 1], a1[(t + 1) * 64 + n], s1);
            s2 = fmaf(gb3[t + 2], a1[(t + 2) * 64 + n], s2);
            s3 = fmaf(gb3[t + 3], a1[(t + 3) * 64 + n], s3);
        }
        bias1p[n] = (s0 + s1) + (s2 + s3);
        return;
    }
    float val;
    if (i < OFF_W2T)       { int li = i;            int n = li >> 7, k = li & 127; val = w1[k * 64 + n]; }
    else if (i < OFF_W3T)  { int li = i - OFF_W2T;  int n = li >> 6, k = li & 63;  val = w2[k * 64 + n]; }
    else if (i < OFF_WCAT) { int li = i - OFF_W3T;  int n = li >> 6, k = li & 63;  val = w3[k * 64 + n]; }
    else if (i < OFF_A2T)  {                        // WCAT[n][k]
        int li = i - OFF_WCAT; int n = li >> 7, k = li & 127;
        if (k >= 64) val = a1[k * 64 + n];          // A1_bot
        else {                                      // (W3 @ A1_top)[k][n]
            float s0 = 0.f, s1 = 0.f, s2 = 0.f, s3 = 0.f;
#pragma unroll
            for (int t = 0; t < 64; t += 4) {
                float4 w = *(const float4*)(w3 + k * 64 + t);
                s0 = fmaf(w.x, a1[t * 64 + n],       s0);
                s1 = fmaf(w.y, a1[(t + 1) * 64 + n], s1);
                s2 = fmaf(w.z, a1[(t + 2) * 64 + n], s2);
                s3 = fmaf(w.w, a1[(t + 3) * 64 + n], s3);
            }
            val = (s0 + s1) + (s2 + s3);
        }
    }
    else if (i < OFF_R1T)  { int li = i - OFF_A2T;  int n = li >> 6, k = li & 63;  val = a2[k * 64 + n]; }
    else if (i < OFF_R2T)  { int li = i - OFF_R1T;  int n = li >> 7, k = li & 127; val = r1[k * 64 + n]; }
    else                   { int li = i - OFF_R2T;  int n = li >> 6, k = li & 63;  val = r2[k * 64 + n]; }
    wt[i] = (bf16)val;
}

// ---------------- fully fused main: gather -> 5 layers -> softmax -> zj -> combine -> out ----------------
extern "C" __global__ void __launch_bounds__(256, 8)
item_main(const int* __restrict__ nodes_v, const int* __restrict__ neigh_u,
          const int* __restrict__ neigh_r,
          const float* __restrict__ embed_u, const float* __restrict__ embed_i,
          const float* __restrict__ embed_r,
          const float* __restrict__ gv_b1, const float* __restrict__ gv_b2,
          const float* __restrict__ gv_b3,
          const float* __restrict__ att_b2, const float* __restrict__ att_w3,
          const float* __restrict__ wr1_b, const float* __restrict__ wr2_b,
          const bf16* __restrict__ wt, const float* __restrict__ bias1p,
          float* __restrict__ out)
{
    // Single overlaid buffer: 19200 B total -> 8 blocks/CU LDS cap.
    __shared__ __align__(16) bf16 Xs[64 * SX];
    __shared__ float qs[64];      // q (f32) for the combine tail
    __shared__ float scs[64];     // attention scores; reused as z2 in tail
    __shared__ float muS[64];     // softmax weights; reused as zj in tail
    __shared__ float zp[4 * 64];  // zj partials

    const int b = blockIdx.x;
    const int tid = threadIdx.x;
    const int lane = tid & 63, wave = tid >> 6;
    const int m = lane & 15, quad = lane >> 4;
    const int rb = wave * 16;
    const int v = nodes_v[b];

    // q A-frags in regs (row-broadcast): qf[t][j] = q[t*32 + quad*8 + j]
    s16x8 qf[2];
#pragma unroll
    for (int t = 0; t < 2; ++t) {
        float4 qa = *(const float4*)(embed_i + v * 64 + t * 32 + quad * 8);
        float4 qb4 = *(const float4*)(embed_i + v * 64 + t * 32 + quad * 8 + 4);
        s16x8 r;
        r[0] = (short)f2b(qa.x);  r[1] = (short)f2b(qa.y);  r[2] = (short)f2b(qa.z);  r[3] = (short)f2b(qa.w);
        r[4] = (short)f2b(qb4.x); r[5] = (short)f2b(qb4.y); r[6] = (short)f2b(qb4.z); r[7] = (short)f2b(qb4.w);
        qf[t] = r;
    }
    if (tid < 64) qs[tid] = embed_i[v * 64 + tid];

    // wave-local gather: wave w stages rows [rb, rb+16); pt -> X[:,0:64], er -> X[:,64:128]
    {
        const int rsub = lane >> 4;   // 4 rows per iter
        const int c = lane & 15;      // 16B chunk (4 floats)
#pragma unroll
        for (int it = 0; it < 4; ++it) {
            int row = rb + it * 4 + rsub;
            float4 vu = make_float4(0.f, 0.f, 0.f, 0.f), vr = vu;
            if (row < L_) {
                int u = neigh_u[b * L_ + row];
                int r = neigh_r[b * L_ + row];
                vu = *(const float4*)(embed_u + u * 64 + c * 4);
                vr = *(const float4*)(embed_r + r * 64 + c * 4);
            }
            uint2 pu, pr;
            pu.x = pack2(vu.x, vu.y); pu.y = pack2(vu.z, vu.w);
            pr.x = pack2(vr.x, vr.y); pr.y = pack2(vr.z, vr.w);
            *(uint2*)(Xs + row * SX + c * 4) = pu;
            *(uint2*)(Xs + row * SX + 64 + c * 4) = pr;
        }
    }

    const bf16* w1t = wt + OFF_W1T;
    const bf16* w2t = wt + OFF_W2T;
    const bf16* w3t = wt + OFF_W3T;
    const bf16* wct = wt + OFF_WCAT;
    const bf16* a2t = wt + OFF_A2T;

    bf16* Xw = Xs + rb * SX;   // this wave's 16-row tile

    // gv1: X[:,0:128] -> h1 -> X[:,64:128]   (er dead after reads; same-wave WAR safe)
    layer<4, true>(Xw, SX, w1t, gv_b1, Xw + 64, SX, lane);
    // gv2: X[:,64:128] -> h2 -> X[:,0:64]
    layer<2, true>(Xw + 64, SX, w2t, gv_b2, Xw, SX, lane);

    // fused gv3 + att1': consume h2; fjt -> X[:,64:128], att1h -> X[:,0:64]
    {
        f32x4 accF[4] = {}, accA[4] = {};
#pragma unroll
        for (int kt = 0; kt < 2; ++kt) {
            s16x8 a = *(const s16x8*)(Xw + m * SX + kt * 32 + quad * 8);
#pragma unroll
            for (int nt = 0; nt < 4; ++nt) {
                s16x8 bF = *(const s16x8*)(w3t + (nt * 16 + m) * 64 + kt * 32 + quad * 8);
                s16x8 bA = *(const s16x8*)(wct + (nt * 16 + m) * 128 + kt * 32 + quad * 8);
                accF[nt] = __builtin_amdgcn_mfma_f32_16x16x32_bf16(a, bF, accF[nt], 0, 0, 0);
                accA[nt] = __builtin_amdgcn_mfma_f32_16x16x32_bf16(a, bA, accA[nt], 0, 0, 0);
            }
        }
#pragma unroll
        for (int kt = 2; kt < 4; ++kt) {
#pragma unroll
            for (int nt = 0; nt < 4; ++nt) {
                s16x8 bA = *(const s16x8*)(wct + (nt * 16 + m) * 128 + kt * 32 + quad * 8);
                accA[nt] = __builtin_amdgcn_mfma_f32_16x16x32_bf16(qf[kt - 2], bA, accA[nt], 0, 0, 0);
            }
        }
#pragma unroll
        for (int nt = 0; nt < 4; ++nt) {
            int c = nt * 16 + m;
            float b3v = gv_b3[c], b1v = bias1p[c];
#pragma unroll
            for (int r4 = 0; r4 < 4; ++r4) {
                int ro = (quad * 4 + r4) * SX;
                Xw[ro + 64 + c] = (bf16)(accF[nt][r4] + b3v);         // fjt (no relu)
                Xw[ro + c] = (bf16)fmaxf(accA[nt][r4] + b1v, 0.f);    // att1h
            }
        }
    }

    // att2 in regs + relu + dot(att_w3) + 16-lane reduce -> scores
    {
        f32x4 acc[4] = {};
#pragma unroll
        for (int kt = 0; kt < 2; ++kt) {
            s16x8 a = *(const s16x8*)(Xw + m * SX + kt * 32 + quad * 8);
#pragma unroll
            for (int nt = 0; nt < 4; ++nt) {
                s16x8 bb = *(const s16x8*)(a2t + (nt * 16 + m) * 64 + kt * 32 + quad * 8);
                acc[nt] = __builtin_amdgcn_mfma_f32_16x16x32_bf16(a, bb, acc[nt], 0, 0, 0);
            }
        }
        float sc[4] = {0.f, 0.f, 0.f, 0.f};
#pragma unroll
        for (int nt = 0; nt < 4; ++nt) {
            int c = nt * 16 + m;
            float b2v = att_b2[c], w3v = att_w3[c];
#pragma unroll
            for (int r4 = 0; r4 < 4; ++r4)
                sc[r4] += fmaxf(acc[nt][r4] + b2v, 0.f) * w3v;
        }
#pragma unroll
        for (int mask = 1; mask < 16; mask <<= 1)
#pragma unroll
            for (int r4 = 0; r4 < 4; ++r4) sc[r4] += __shfl_xor(sc[r4], mask);
        if (m == 0) {
#pragma unroll
            for (int r4 = 0; r4 < 4; ++r4) scs[rb + quad * 4 + r4] = sc[r4];
        }
    }
    __syncthreads();

    // softmax over neighbors (att_b3 dropped: softmax is shift-invariant)
    if (wave == 0) {
        float s = (lane < L_) ? scs[lane] : -1e30f;
        float mx = s;
#pragma unroll
        for (int off = 32; off; off >>= 1) mx = fmaxf(mx, __shfl_xor(mx, off));
        float e = (lane < L_) ? __expf(s - mx) : 0.f;
        float sum = e;
#pragma unroll
        for (int off = 32; off; off >>= 1) sum += __shfl_xor(sum, off);
        muS[lane] = e / sum;
    }
    __syncthreads();

    // zj partials: wave w reduces its own 16 fjt rows
    {
        float z = 0.f;
#pragma unroll
        for (int i = 0; i < 16; ++i) {
            int l = rb + i;
            z += (float)Xs[l * SX + 64 + lane] * muS[l];
        }
        zp[wave * 64 + lane] = z;
    }
    __syncthreads();

    // combine tail on wave 0: out = relu(relu([zj|q] @ wr1 + b1) @ wr2 + b2)
    if (wave == 0) {
        float z = zp[lane] + zp[64 + lane] + zp[128 + lane] + zp[192 + lane];
        muS[lane] = z;   // share zj (same-wave in-order)

        float accz = wr1_b[lane];
        const bf16* r1 = wt + OFF_R1T + lane * 128;
#pragma unroll
        for (int k8 = 0; k8 < 8; ++k8) {
            b16x8 wv = *(const b16x8*)(r1 + k8 * 8);
#pragma unroll
            for (int j = 0; j < 8; ++j) accz = fmaf((float)wv[j], muS[k8 * 8 + j], accz);
        }
#pragma unroll
        for (int k8 = 0; k8 < 8; ++k8) {
            b16x8 wv = *(const b16x8*)(r1 + 64 + k8 * 8);
#pragma unroll
            for (int j = 0; j < 8; ++j) accz = fmaf((float)wv[j], qs[k8 * 8 + j], accz);
        }
        accz = fmaxf(accz, 0.f);
        scs[lane] = accz;   // share z2 (same-wave in-order)

        float acco = wr2_b[lane];
        const bf16* r2 = wt + OFF_R2T + lane * 64;
#pragma unroll
        for (int k8 = 0; k8 < 8; ++k8) {
            b16x8 wv = *(const b16x8*)(r2 + k8 * 8);
#pragma unroll
            for (int j = 0; j < 8; ++j) acco = fmaf((float)wv[j], scs[k8 * 8 + j], acco);
        }
        out[b * 64 + lane] = fmaxf(acco, 0.f);
    }
}

extern "C" void kernel_launch(void* const* d_in, const int* in_sizes, int n_in,
                              void* d_out, int out_size, void* d_ws, size_t ws_size,
                              hipStream_t stream)
{
    const int* nodes_v = (const int*)d_in[0];
    const int* neigh_u = (const int*)d_in[1];
    const int* neigh_r = (const int*)d_in[2];
    const float* embed_u = (const float*)d_in[3];
    const float* embed_i = (const float*)d_in[4];
    const float* embed_r = (const float*)d_in[5];
    const float* gv_w1  = (const float*)d_in[6];  const float* gv_b1 = (const float*)d_in[7];
    const float* gv_w2  = (const float*)d_in[8];  const float* gv_b2 = (const float*)d_in[9];
    const float* gv_w3  = (const float*)d_in[10]; const float* gv_b3 = (const float*)d_in[11];
    const float* att_w1 = (const float*)d_in[12]; const float* att_b1 = (const float*)d_in[13];
    const float* att_w2 = (const float*)d_in[14]; const float* att_b2 = (const float*)d_in[15];
    const float* att_w3 = (const float*)d_in[16]; const float* att_b3 = (const float*)d_in[17];
    const float* wr1_w  = (const float*)d_in[18]; const float* wr1_b = (const float*)d_in[19];
    const float* wr2_w  = (const float*)d_in[20]; const float* wr2_b = (const float*)d_in[21];
    (void)att_b3;

    bf16* wt      = (bf16*)d_ws;
    float* bias1p = (float*)((char*)d_ws + BIAS1P_BYTE);

    prep_weights<<<(WT_TOTAL + 64 + 255) / 256, 256, 0, stream>>>(
        gv_w1, gv_w2, gv_w3, att_w1, att_w2, wr1_w, wr2_w, gv_b3, att_b1, wt, bias1p);
    item_main<<<B_, 256, 0, stream>>>(nodes_v, neigh_u, neigh_r, embed_u, embed_i, embed_r,
                                      gv_b1, gv_b2, gv_b3, att_b2, att_w3,
                                      wr1_b, wr2_b, wt, bias1p, (float*)d_out);
}